// Round 1
// baseline (1248.098 us; speedup 1.0000x reference)
//
#include <hip/hip_runtime.h>
#include <hip/hip_bf16.h>
#include <math.h>

#define B_ 8
#define L_ 2048
#define E_ 100
#define F_ 256
#define KW 9
#define Y_ 8921
#define YP 8960      // Y padded to 70*128
#define KC 928       // conv K padded: 9*100=900 -> 928 (29 K-steps of 32)
#define MC 16384     // B*L

typedef __bf16 bf16x8 __attribute__((ext_vector_type(8)));
typedef float f32x4 __attribute__((ext_vector_type(4)));

__device__ __forceinline__ unsigned short f2bf(float v) {
  __hip_bfloat16 h = __float2bfloat16(v);
  return *reinterpret_cast<unsigned short*>(&h);
}

__device__ __forceinline__ void gld_lds16(const unsigned short* g, unsigned short* l) {
  __builtin_amdgcn_global_load_lds((const __attribute__((address_space(1))) void*)g,
                                   (__attribute__((address_space(3))) void*)l,
                                   16, 0, 0);
}

// Stage a 128-row x 32-col bf16 tile (row-major, stride STRIDE elements) into LDS.
// LDS layout: [128][32] contiguous. 512 chunks of 16B, 256 threads -> 2 rounds.
// Per wave: lds addr = uniform base + lane*16, matching global_load_lds semantics.
template <int STRIDE>
__device__ __forceinline__ void stage_tile(const unsigned short* __restrict__ g,
                                           unsigned short* __restrict__ lds, int tid) {
#pragma unroll
  for (int r = 0; r < 2; ++r) {
    int c = r * 256 + tid;
    gld_lds16(g + (size_t)(c >> 2) * STRIDE + (c & 3) * 8, lds + c * 8);
  }
}

// ---------------- im2col: [B*L, 928] bf16, direct from embedding gather ------
__global__ __launch_bounds__(256) void im2col_kernel(const int* __restrict__ x,
                                                     const float* __restrict__ embedW,
                                                     unsigned short* __restrict__ im) {
  int idx = blockIdx.x * 256 + threadIdx.x;  // < 16384*928 = 15,204,352
  if (idx >= MC * KC) return;
  int row = idx / KC, kk = idx - row * KC;
  float v = 0.f;
  if (kk < 900) {
    int k = kk / 100, e = kk - k * 100;
    int b = row >> 11, l = row & 2047;
    int ls = l + k - 4;
    if (ls >= 0 && ls < L_) v = embedW[(size_t)x[b * L_ + ls] * E_ + e];
  }
  im[idx] = f2bf(v);
}

// ---------------- pack conv_w [F,E,K] -> wconv [F][k*100+e] bf16 -------------
__global__ __launch_bounds__(256) void wpack_kernel(const float* __restrict__ convw,
                                                    unsigned short* __restrict__ wc) {
  int idx = blockIdx.x * 256 + threadIdx.x;  // < 256*928
  if (idx >= F_ * KC) return;
  int f = idx / KC, kk = idx - f * KC;
  float v = 0.f;
  if (kk < 900) {
    int k = kk / 100, e = kk - k * 100;
    v = convw[f * 900 + e * 9 + k];
  }
  wc[idx] = f2bf(v);
}

// ---------------- pack U_w / final_w to bf16, padded to 8960 rows ------------
__global__ __launch_bounds__(256) void ufpack_kernel(const float* __restrict__ Uw,
                                                     const float* __restrict__ Fww,
                                                     unsigned short* __restrict__ Ub,
                                                     unsigned short* __restrict__ Fwb) {
  int idx = blockIdx.x * 256 + threadIdx.x;  // < 2*8960*256
  if (idx >= 2 * YP * F_) return;
  int sel = idx / (YP * F_);
  int r = idx - sel * (YP * F_);
  int y = r / F_, f = r - y * F_;
  float v = (y < Y_) ? (sel ? Fww[y * F_ + f] : Uw[y * F_ + f]) : 0.f;
  (sel ? Fwb : Ub)[r] = f2bf(v);
}

// ---------------- conv GEMM: h[m,n] = tanh(im2col * wconv^T + b) -------------
__global__ __launch_bounds__(256) void conv_gemm(const unsigned short* __restrict__ A,
                                                 const unsigned short* __restrict__ Bt,
                                                 const float* __restrict__ convb,
                                                 unsigned short* __restrict__ hb) {
  __shared__ unsigned short As[128 * 32], Bs[128 * 32];
  const int mt = blockIdx.x, nt = blockIdx.y, tid = threadIdx.x;
  const unsigned short* Ag = A + (size_t)mt * 128 * KC;
  const unsigned short* Bg = Bt + (size_t)nt * 128 * KC;
  f32x4 acc[4][4] = {};
  const int lane = tid & 63, wv = tid >> 6;
  const int wy = wv >> 1, wx = wv & 1, lr = lane & 15, lq = lane >> 4;
  for (int kt = 0; kt < 29; ++kt) {
    __syncthreads();
    stage_tile<KC>(Ag + kt * 32, As, tid);
    stage_tile<KC>(Bg + kt * 32, Bs, tid);
    __syncthreads();
    bf16x8 a[4], bb[4];
#pragma unroll
    for (int i = 0; i < 4; ++i) a[i] = *(const bf16x8*)&As[(wy * 64 + i * 16 + lr) * 32 + lq * 8];
#pragma unroll
    for (int j = 0; j < 4; ++j) bb[j] = *(const bf16x8*)&Bs[(wx * 64 + j * 16 + lr) * 32 + lq * 8];
#pragma unroll
    for (int i = 0; i < 4; ++i)
#pragma unroll
      for (int j = 0; j < 4; ++j)
        acc[i][j] = __builtin_amdgcn_mfma_f32_16x16x32_bf16(a[i], bb[j], acc[i][j], 0, 0, 0);
  }
#pragma unroll
  for (int j = 0; j < 4; ++j) {
    const int n = nt * 128 + wx * 64 + j * 16 + lr;
    const float cb = convb[n];
#pragma unroll
    for (int i = 0; i < 4; ++i)
#pragma unroll
      for (int r = 0; r < 4; ++r) {
        const int m = mt * 128 + wy * 64 + i * 16 + lq * 4 + r;
        hb[(size_t)m * F_ + n] = f2bf(tanhf(acc[i][j][r] + cb));
      }
  }
}

// ---------------- pass 1: scores GEMM + row sums of exp ----------------------
__global__ __launch_bounds__(256) void scores_sum(const unsigned short* __restrict__ U,
                                                  const unsigned short* __restrict__ hb,
                                                  float* __restrict__ Spart) {
  __shared__ unsigned short As[128 * 32], Bs[128 * 32];
  __shared__ float rsum[128][2];
  const int yt = blockIdx.x, lt = blockIdx.y, b = blockIdx.z, tid = threadIdx.x;
  const unsigned short* Ag = U + (size_t)yt * 128 * F_;
  const unsigned short* Bg = hb + ((size_t)b * L_ + lt * 128) * F_;
  f32x4 acc[4][4] = {};
  const int lane = tid & 63, wv = tid >> 6;
  const int wy = wv >> 1, wx = wv & 1, lr = lane & 15, lq = lane >> 4;
  for (int kt = 0; kt < 8; ++kt) {
    __syncthreads();
    stage_tile<F_>(Ag + kt * 32, As, tid);
    stage_tile<F_>(Bg + kt * 32, Bs, tid);
    __syncthreads();
    bf16x8 a[4], bb[4];
#pragma unroll
    for (int i = 0; i < 4; ++i) a[i] = *(const bf16x8*)&As[(wy * 64 + i * 16 + lr) * 32 + lq * 8];
#pragma unroll
    for (int j = 0; j < 4; ++j) bb[j] = *(const bf16x8*)&Bs[(wx * 64 + j * 16 + lr) * 32 + lq * 8];
#pragma unroll
    for (int i = 0; i < 4; ++i)
#pragma unroll
      for (int j = 0; j < 4; ++j)
        acc[i][j] = __builtin_amdgcn_mfma_f32_16x16x32_bf16(a[i], bb[j], acc[i][j], 0, 0, 0);
  }
#pragma unroll
  for (int i = 0; i < 4; ++i)
#pragma unroll
    for (int r = 0; r < 4; ++r) {
      float rs = 0.f;
#pragma unroll
      for (int j = 0; j < 4; ++j) rs += __expf(acc[i][j][r]);
#pragma unroll
      for (int off = 1; off < 16; off <<= 1) rs += __shfl_xor(rs, off);
      if (lr == 0) rsum[wy * 64 + i * 16 + lq * 4 + r][wx] = rs;
    }
  __syncthreads();
  if (tid < 128)
    Spart[((size_t)b * YP + yt * 128 + tid) * 16 + lt] = rsum[tid][0] + rsum[tid][1];
}

__global__ __launch_bounds__(256) void sinv_kernel(const float* __restrict__ Spart,
                                                   float* __restrict__ Sinv) {
  int idx = blockIdx.x * 256 + threadIdx.x;
  if (idx >= B_ * YP) return;
  float s = 0.f;
#pragma unroll
  for (int t = 0; t < 16; ++t) s += Spart[(size_t)idx * 16 + t];
  Sinv[idx] = 1.f / s;
}

// ------ pass 2: dual GEMM (scores + g) -> alpha write + yhat numerator -------
__global__ __launch_bounds__(256) void dual_gemm(const unsigned short* __restrict__ U,
                                                 const unsigned short* __restrict__ Fw,
                                                 const unsigned short* __restrict__ hb,
                                                 const float* __restrict__ Sinv,
                                                 float* __restrict__ alpha,
                                                 float* __restrict__ Npart) {
  __shared__ unsigned short As[128 * 32], As2[128 * 32], Bs[128 * 32];
  __shared__ float rsum[128][2];
  __shared__ float sinv[128];
  const int yt = blockIdx.x, lt = blockIdx.y, b = blockIdx.z, tid = threadIdx.x;
  if (tid < 128) sinv[tid] = Sinv[b * YP + yt * 128 + tid];
  const unsigned short* Ag = U + (size_t)yt * 128 * F_;
  const unsigned short* Ag2 = Fw + (size_t)yt * 128 * F_;
  const unsigned short* Bg = hb + ((size_t)b * L_ + lt * 128) * F_;
  f32x4 accs[4][4] = {}, accg[4][4] = {};
  const int lane = tid & 63, wv = tid >> 6;
  const int wy = wv >> 1, wx = wv & 1, lr = lane & 15, lq = lane >> 4;
  for (int kt = 0; kt < 8; ++kt) {
    __syncthreads();
    stage_tile<F_>(Ag + kt * 32, As, tid);
    stage_tile<F_>(Ag2 + kt * 32, As2, tid);
    stage_tile<F_>(Bg + kt * 32, Bs, tid);
    __syncthreads();
    bf16x8 a1[4], a2[4], bb[4];
#pragma unroll
    for (int i = 0; i < 4; ++i) {
      a1[i] = *(const bf16x8*)&As[(wy * 64 + i * 16 + lr) * 32 + lq * 8];
      a2[i] = *(const bf16x8*)&As2[(wy * 64 + i * 16 + lr) * 32 + lq * 8];
    }
#pragma unroll
    for (int j = 0; j < 4; ++j) bb[j] = *(const bf16x8*)&Bs[(wx * 64 + j * 16 + lr) * 32 + lq * 8];
#pragma unroll
    for (int i = 0; i < 4; ++i)
#pragma unroll
      for (int j = 0; j < 4; ++j) {
        accs[i][j] = __builtin_amdgcn_mfma_f32_16x16x32_bf16(a1[i], bb[j], accs[i][j], 0, 0, 0);
        accg[i][j] = __builtin_amdgcn_mfma_f32_16x16x32_bf16(a2[i], bb[j], accg[i][j], 0, 0, 0);
      }
  }
#pragma unroll
  for (int i = 0; i < 4; ++i)
#pragma unroll
    for (int r = 0; r < 4; ++r) {
      const int ml = wy * 64 + i * 16 + lq * 4 + r;
      const int y = yt * 128 + ml;
      const float si = sinv[ml];
      float ns = 0.f;
#pragma unroll
      for (int j = 0; j < 4; ++j) {
        const float av = __expf(accs[i][j][r]) * si;
        ns += av * accg[i][j][r];
        if (y < Y_) {
          const int l = lt * 128 + wx * 64 + j * 16 + lr;
          alpha[((size_t)b * Y_ + y) * L_ + l] = av;
        }
      }
#pragma unroll
      for (int off = 1; off < 16; off <<= 1) ns += __shfl_xor(ns, off);
      if (lr == 0) rsum[ml][wx] = ns;
    }
  __syncthreads();
  if (tid < 128)
    Npart[((size_t)b * YP + yt * 128 + tid) * 16 + lt] = rsum[tid][0] + rsum[tid][1];
}

// ---------------- yhat + loss ------------------------------------------------
__global__ __launch_bounds__(256) void yhat_kernel(const float* __restrict__ Npart,
                                                   const float* __restrict__ Fb,
                                                   float* __restrict__ yhat) {
  int idx = blockIdx.x * 256 + threadIdx.x;
  if (idx >= B_ * Y_) return;
  int b = idx / Y_, y = idx - b * Y_;
  float s = Fb[y];
#pragma unroll
  for (int t = 0; t < 16; ++t) s += Npart[((size_t)b * YP + y) * 16 + t];
  yhat[idx] = s;
}

__global__ __launch_bounds__(256) void loss_part_kernel(const float* __restrict__ yhat,
                                                        const float* __restrict__ target,
                                                        float* __restrict__ part) {
  __shared__ float red[256];
  float s = 0.f;
  for (int i = blockIdx.x * 256 + threadIdx.x; i < B_ * Y_; i += gridDim.x * 256) {
    float yh = yhat[i], t = target[i];
    s += fmaxf(yh, 0.f) - yh * t + log1pf(expf(-fabsf(yh)));
  }
  red[threadIdx.x] = s;
  __syncthreads();
  for (int o = 128; o > 0; o >>= 1) {
    if (threadIdx.x < o) red[threadIdx.x] += red[threadIdx.x + o];
    __syncthreads();
  }
  if (threadIdx.x == 0) part[blockIdx.x] = red[0];
}

__global__ __launch_bounds__(128) void loss_final_kernel(const float* __restrict__ part,
                                                         float* __restrict__ loss) {
  __shared__ float red[128];
  red[threadIdx.x] = part[threadIdx.x];
  __syncthreads();
  for (int o = 64; o > 0; o >>= 1) {
    if (threadIdx.x < o) red[threadIdx.x] += red[threadIdx.x + o];
    __syncthreads();
  }
  if (threadIdx.x == 0) loss[0] = red[0] * (1.f / (float)(B_ * Y_));
}

extern "C" void kernel_launch(void* const* d_in, const int* in_sizes, int n_in,
                              void* d_out, int out_size, void* d_ws, size_t ws_size,
                              hipStream_t stream) {
  const int* x = (const int*)d_in[0];
  const float* target = (const float*)d_in[1];
  const float* embedW = (const float*)d_in[2];
  const float* convw = (const float*)d_in[3];
  const float* convb = (const float*)d_in[4];
  const float* Uw = (const float*)d_in[5];
  const float* Fww = (const float*)d_in[6];
  const float* Fb = (const float*)d_in[7];

  float* out = (float*)d_out;
  float* yhat = out;                 // [B*Y] = 71368
  float* loss = out + 71368;         // [1]
  float* alpha = out + 71369;        // [B*Y*L]

  char* w = (char*)d_ws;
  size_t off = 0;
  auto alloc = [&](size_t bytes) -> void* {
    void* p = w + off;
    off += (bytes + 255) & ~(size_t)255;
    return p;
  };
  unsigned short* im2col = (unsigned short*)alloc((size_t)MC * KC * 2);  // 30.4 MB
  unsigned short* wconv = (unsigned short*)alloc((size_t)F_ * KC * 2);   // 0.5 MB
  unsigned short* Ub = (unsigned short*)alloc((size_t)YP * F_ * 2);      // 4.6 MB
  unsigned short* Fwb = (unsigned short*)alloc((size_t)YP * F_ * 2);     // 4.6 MB
  unsigned short* hb = (unsigned short*)alloc((size_t)MC * F_ * 2);      // 8.4 MB
  float* Spart = (float*)alloc((size_t)B_ * YP * 16 * 4);                // 4.6 MB
  float* Sinv = (float*)alloc((size_t)B_ * YP * 4);                      // 0.3 MB
  float* Npart = (float*)alloc((size_t)B_ * YP * 16 * 4);                // 4.6 MB
  float* lpart = (float*)alloc(128 * 4);

  im2col_kernel<<<(MC * KC + 255) / 256, 256, 0, stream>>>(x, embedW, im2col);
  wpack_kernel<<<(F_ * KC + 255) / 256, 256, 0, stream>>>(convw, wconv);
  ufpack_kernel<<<(2 * YP * F_ + 255) / 256, 256, 0, stream>>>(Uw, Fww, Ub, Fwb);
  conv_gemm<<<dim3(128, 2), 256, 0, stream>>>(im2col, wconv, convb, hb);
  scores_sum<<<dim3(70, 16, 8), 256, 0, stream>>>(Ub, hb, Spart);
  sinv_kernel<<<(B_ * YP + 255) / 256, 256, 0, stream>>>(Spart, Sinv);
  dual_gemm<<<dim3(70, 16, 8), 256, 0, stream>>>(Ub, Fwb, hb, Sinv, alpha, Npart);
  yhat_kernel<<<(B_ * Y_ + 255) / 256, 256, 0, stream>>>(Npart, Fb, yhat);
  loss_part_kernel<<<128, 256, 0, stream>>>(yhat, target, lpart);
  loss_final_kernel<<<1, 128, 0, stream>>>(lpart, loss);
}